// Round 8
// baseline (121.527 us; speedup 1.0000x reference)
//
#include <hip/hip_runtime.h>
#include <math.h>

// Problem constants
constexpr int NH    = 778;    // hand verts per batch
constexpr int T     = 16;     // hand points per tile
constexpr int G     = 4;      // tiles per block -> 64 hand points / block
constexpr int NBX   = (NH + G * T - 1) / (G * T);   // 13
constexpr int BLK   = 256;    // 4 waves
constexpr int CHUNK = 2048;   // obj points per block chunk (32 KB LDS)
constexpr int LPP   = CHUNK / BLK;   // 8 obj points per lane per pass

// ---------------------------------------------------------------------------
// Main NN kernel.
// R6/R7 post-mortem: R6 was DS-pipe-bound (shfl epilogue), R7 fixed that but
// its fully-unrolled ~20 KB body blew the 32 KB L1 I-cache (instruction-fetch
// bound). R8: compact body (~5 KB: g-loop NOT unrolled) + obj chunk staged in
// LDS once per block, read per-lane as ds_read_b128 (stride 16 B = 2-way bank
// aliasing = free, fine-grained lgkmcnt pipelining — NOT the R1-R4 broadcast
// pattern). Math per obj-pair (2 points): 6 fma + 1 v_min3 = 3.5 VALU/pair:
//   d2' = |o|^2 - 2 h.o   (|h|^2 folded in the epilogue)
// Epilogue per tile: LDS transpose (stride-65 rows, conflict-free) + 2 shfl,
// then pre-checked atomicMin (uint ordering valid for non-negative floats).
// ---------------------------------------------------------------------------
__global__ __launch_bounds__(BLK) void nn_min_kernel(
    const float* __restrict__ hand,  // [B, NH, 3]
    const float* __restrict__ obj,   // [B, V, 3]
    unsigned int* __restrict__ minb, // [B*NH]
    int V)
{
    __shared__ float4 s_obj[CHUNK];        // 32 KB: (x,y,z,|o|^2)
    __shared__ float  s_red[4][16 * 65];   // 16.6 KB: per-wave transpose
    const int bx   = blockIdx.x;   // hand tile group
    const int c    = blockIdx.y;   // obj chunk
    const int b    = blockIdx.z;   // batch
    const int tid  = threadIdx.x;
    const int wave = tid >> 6;
    const int lane = tid & 63;

    // stage chunk -> LDS (coalesced per-lane loads; sentinel past V)
    const int j0  = c * CHUNK;
    const int cnt = min(CHUNK, V - j0);
    const float* op = obj + ((size_t)b * V + j0) * 3;
    for (int i = tid; i < CHUNK; i += BLK) {
        if (i < cnt) {
            const float x = op[3 * i + 0];
            const float y = op[3 * i + 1];
            const float z = op[3 * i + 2];
            s_obj[i] = make_float4(x, y, z, fmaf(x, x, fmaf(y, y, z * z)));
        } else {
            s_obj[i] = make_float4(0.f, 0.f, 0.f, 3.4e38f);  // never the min
        }
    }
    __syncthreads();

    const float* hb = hand + (size_t)b * NH * 3;
    float* sw = &s_red[wave][0];
    const int r   = lane & 15;
    const int seg = lane >> 4;

#pragma unroll 1   // keep the resident body I$-small (~5 KB)
    for (int g = 0; g < G; ++g) {
        // hand tile (uniform addresses; scalar or broadcast loads, once/pass)
        float hx[T], hy[T], hz[T], hq[T], m[T];
#pragma unroll
        for (int t = 0; t < T; ++t) {
            const int h = min((bx * G + g) * T + t, NH - 1);
            const float x = hb[3 * h + 0];
            const float y = hb[3 * h + 1];
            const float z = hb[3 * h + 2];
            hx[t] = -2.f * x; hy[t] = -2.f * y; hz[t] = -2.f * z;
            hq[t] = fmaf(x, x, fmaf(y, y, z * z));
            m[t]  = 3.4e38f;
        }

        for (int k = 0; k < LPP; k += 2) {
            // per-lane LDS reads: b128, stride 16 B (2-way aliasing = free)
            const float4 o0 = s_obj[(k + 0) * BLK + tid];
            const float4 o1 = s_obj[(k + 1) * BLK + tid];
#pragma unroll
            for (int t = 0; t < T; ++t) {
                float a0 = fmaf(hx[t], o0.x, o0.w);
                a0 = fmaf(hy[t], o0.y, a0);
                a0 = fmaf(hz[t], o0.z, a0);
                float a1 = fmaf(hx[t], o1.x, o1.w);
                a1 = fmaf(hy[t], o1.y, a1);
                a1 = fmaf(hz[t], o1.z, a1);
                m[t] = fminf(fminf(a0, a1), m[t]);   // v_min3
            }
        }

        // fold |h|^2 and transpose within the wave (rows stride 65)
#pragma unroll
        for (int t = 0; t < T; ++t) sw[t * 65 + lane] = m[t] + hq[t];
        __builtin_amdgcn_wave_barrier();

        float v = 3.4e38f;
        const int base = r * 65 + seg * 16;
#pragma unroll
        for (int j = 0; j < 16; ++j) v = fminf(v, sw[base + j]);
        __builtin_amdgcn_wave_barrier();   // before next pass overwrites

        v = fminf(v, __shfl_xor(v, 16));
        v = fminf(v, __shfl_xor(v, 32));

        if (seg == 0) {
            const int hidx = (bx * G + g) * T + r;
            if (hidx < NH) {
                const unsigned bits = __float_as_uint(fmaxf(v, 0.f));
                unsigned int* p = &minb[b * NH + hidx];
                // stale read >= true min => skip when bits >= *p is safe
                if (bits < *((volatile unsigned int*)p)) atomicMin(p, bits);
            }
        }
    }
}

// Final reduction -> 6 scalar outputs
__global__ __launch_bounds__(256) void finalize_kernel(
    const unsigned int* __restrict__ minb, float* __restrict__ out, int B)
{
    constexpr float COLL = 0.005f;
    constexpr float CONT = 0.01f;
    const int total = B * NH;
    const int tid = threadIdx.x;

    double sum_d = 0.0, pen_sum = 0.0, att_sum = 0.0;
    int pen_cnt = 0, att_cnt = 0;
    for (int i = tid; i < total; i += 256) {
        const float d = sqrtf(__uint_as_float(minb[i]));
        sum_d += (double)d;
        if (d < COLL) { const float t = COLL - d; pen_sum += (double)(t * t); pen_cnt++; }
        const int n = i % NH;
        const bool isc = (n == 745) | (n == 317) | (n == 444) | (n == 556) |
                         (n == 673) | (n == 95)  | (n == 182) | (n == 234) |
                         (n == 279) | (n == 320);
        if (isc & (d > COLL) & (d < CONT)) { att_sum += (double)(d * d); att_cnt++; }
    }

    __shared__ double sd[256], sp[256], sa[256];
    __shared__ int    cp[256], ca[256];
    sd[tid] = sum_d; sp[tid] = pen_sum; sa[tid] = att_sum;
    cp[tid] = pen_cnt; ca[tid] = att_cnt;
    __syncthreads();
    for (int off = 128; off > 0; off >>= 1) {
        if (tid < off) {
            sd[tid] += sd[tid + off]; sp[tid] += sp[tid + off];
            sa[tid] += sa[tid + off];
            cp[tid] += cp[tid + off]; ca[tid] += ca[tid + off];
        }
        __syncthreads();
    }
    if (tid == 0) {
        const double pen_loss = cp[0] > 0 ? sp[0] / (double)cp[0] : 0.0;
        const double att_loss = ca[0] > 0 ? sa[0] / (double)ca[0] : 0.0;
        out[0] = (float)(100.0 * pen_loss + 10.0 * att_loss);
        out[1] = (float)pen_loss;
        out[2] = (float)att_loss;
        out[3] = (float)(sd[0] / (double)total);
        out[4] = (float)ca[0];
        out[5] = (float)cp[0];
    }
}

extern "C" void kernel_launch(void* const* d_in, const int* in_sizes, int n_in,
                              void* d_out, int out_size, void* d_ws, size_t ws_size,
                              hipStream_t stream) {
    const float* hand = (const float*)d_in[0];  // [B, 778, 3] fp32
    const float* obj  = (const float*)d_in[1];  // [B, V, 3]   fp32
    // d_in[2]/d_in[3] (faces): unused by the loss

    const int B = in_sizes[0] / (NH * 3);
    const int V = in_sizes[1] / (B * 3);
    const int nchunks = (V + CHUNK - 1) / CHUNK;

    unsigned int* minb = (unsigned int*)d_ws;   // [B*NH] min-d2 bit patterns

    // init mins to 0x7F7F7F7F (~3.39e38f; > any real d2)
    hipMemsetAsync(d_ws, 0x7F, (size_t)B * NH * sizeof(unsigned int), stream);

    dim3 grid(NBX, nchunks, B);
    nn_min_kernel<<<grid, BLK, 0, stream>>>(hand, obj, minb, V);
    finalize_kernel<<<1, 256, 0, stream>>>(minb, (float*)d_out, B);
}

// Round 9
// 112.391 us; speedup vs baseline: 1.0813x; 1.0813x over previous
//
#include <hip/hip_runtime.h>
#include <math.h>

// Problem constants
constexpr int NH     = 778;   // hand verts per batch
constexpr int T      = 16;    // hand points per tile (SGPR-resident)
constexpr int G      = 4;     // tiles per block -> 64 hand points
constexpr int NBX    = (NH + G * T - 1) / (G * T);   // 13
constexpr int BLK    = 256;   // 4 waves
constexpr int CHUNKP = 2560;  // obj points per block chunk
constexpr int LPP    = CHUNKP / BLK;   // 10 obj points per lane (40 VGPRs)

// ---------------------------------------------------------------------------
// NN kernel — synthesis of R1-R8 measurements:
//  * obj points stream PER-LANE through VMEM into registers (R6/R7's win;
//    broadcast LDS/SMEM inner loops stall on drain-waits, R1-R5).
//  * hand tiles load via uniform s_load into SGPRs (R5-proven); the -2x
//    scaling lives on the per-lane obj registers so no scalar-FP op needed.
//  * g-loop NOT unrolled: resident body ~5 KB, I$-safe (R7 blew 32 KB I$).
//  * epilogue = per-wave LDS transpose (stride-65 rows, conflict-free) + 2
//    shfl (R7/R8-proven correct), NOT 96 ds_swizzles (R6's 23 us DS cost).
// Math per obj-point-pair per hand point: 6 fma + 1 v_min3 = 3.5 VALU ops:
//   d2' = |o|^2 - 2 h.o     (|h|^2 folded in the epilogue)
// atomicMin on uint bit patterns (valid order for non-negative floats),
// gated by a plain-load pre-check.
// ---------------------------------------------------------------------------
__global__ __launch_bounds__(BLK) void nn_min_kernel(
    const float* __restrict__ hand,  // [B, NH, 3]
    const float* __restrict__ obj,   // [B, V, 3]
    unsigned int* __restrict__ minb, // [B*NH]
    int V)
{
    __shared__ float s_red[4][16 * 65];   // 16.6 KB per-wave transpose
    const int bx   = blockIdx.x;   // hand tile group
    const int c    = blockIdx.y;   // obj chunk
    const int b    = blockIdx.z;   // batch
    const int tid  = threadIdx.x;
    const int wave = tid >> 6;
    const int lane = tid & 63;
    const int r    = lane & 15;
    const int seg  = lane >> 4;

    // per-lane obj stash: (-2x,-2y,-2z,q), q=inf sentinel for ragged tail
    const float* ob = obj + (size_t)b * V * 3;
    const int base = c * CHUNKP + tid;
    float ox[LPP], oy[LPP], oz[LPP], oq[LPP];
#pragma unroll
    for (int k = 0; k < LPP; ++k) {
        const int idx = base + k * BLK;
        const int j = min(idx, V - 1);          // clamped: always in-bounds
        const float x = ob[3 * j + 0];
        const float y = ob[3 * j + 1];
        const float z = ob[3 * j + 2];
        ox[k] = -2.f * x; oy[k] = -2.f * y; oz[k] = -2.f * z;
        oq[k] = (idx < V) ? fmaf(x, x, fmaf(y, y, z * z)) : 3.4e38f;
    }

    const float* hb = hand + (size_t)b * NH * 3;  // uniform base
    float* sw = &s_red[wave][0];

#pragma unroll 1   // keep resident body small: I$-safe
    for (int g = 0; g < G; ++g) {
        // hand tile: uniform addresses -> s_load into SGPRs
        float hx[T], hy[T], hz[T];
#pragma unroll
        for (int t = 0; t < T; ++t) {
            const int h = min((bx * G + g) * T + t, NH - 1);
            hx[t] = hb[3 * h + 0];
            hy[t] = hb[3 * h + 1];
            hz[t] = hb[3 * h + 2];
        }

        float m[T];
#pragma unroll
        for (int t = 0; t < T; ++t) m[t] = 3.4e38f;

#pragma unroll
        for (int k = 0; k < LPP; k += 2) {
#pragma unroll
            for (int t = 0; t < T; ++t) {
                // each v_fma: one SGPR (h*), VGPR src/acc
                float a0 = fmaf(ox[k], hx[t], oq[k]);
                a0 = fmaf(oy[k], hy[t], a0);
                a0 = fmaf(oz[k], hz[t], a0);
                float a1 = fmaf(ox[k + 1], hx[t], oq[k + 1]);
                a1 = fmaf(oy[k + 1], hy[t], a1);
                a1 = fmaf(oz[k + 1], hz[t], a1);
                m[t] = fminf(fminf(a0, a1), m[t]);   // v_min3
            }
        }

        // fold |h|^2, transpose within the wave (row stride 65: conflict-free)
#pragma unroll
        for (int t = 0; t < T; ++t) {
            const float hq = fmaf(hx[t], hx[t], fmaf(hy[t], hy[t], hz[t] * hz[t]));
            sw[t * 65 + lane] = m[t] + hq;
        }
        __builtin_amdgcn_wave_barrier();

        float v = 3.4e38f;
        const int rbase = r * 65 + seg * 16;
#pragma unroll
        for (int j = 0; j < 16; ++j) v = fminf(v, sw[rbase + j]);
        __builtin_amdgcn_wave_barrier();   // before next tile overwrites

        v = fminf(v, __shfl_xor(v, 16));
        v = fminf(v, __shfl_xor(v, 32));

        if (seg == 0) {
            const int hidx = (bx * G + g) * T + r;
            if (hidx < NH) {
                const unsigned bits = __float_as_uint(fmaxf(v, 0.f));
                unsigned int* p = &minb[b * NH + hidx];
                // stale read >= true min => skipping when bits >= *p is safe
                if (bits < *((volatile unsigned int*)p)) atomicMin(p, bits);
            }
        }
    }
}

// Final reduction -> 6 scalar outputs
__global__ __launch_bounds__(256) void finalize_kernel(
    const unsigned int* __restrict__ minb, float* __restrict__ out, int B)
{
    constexpr float COLL = 0.005f;
    constexpr float CONT = 0.01f;
    const int total = B * NH;
    const int tid = threadIdx.x;

    double sum_d = 0.0, pen_sum = 0.0, att_sum = 0.0;
    int pen_cnt = 0, att_cnt = 0;
    for (int i = tid; i < total; i += 256) {
        const float d = sqrtf(__uint_as_float(minb[i]));
        sum_d += (double)d;
        if (d < COLL) { const float t = COLL - d; pen_sum += (double)(t * t); pen_cnt++; }
        const int n = i % NH;
        const bool isc = (n == 745) | (n == 317) | (n == 444) | (n == 556) |
                         (n == 673) | (n == 95)  | (n == 182) | (n == 234) |
                         (n == 279) | (n == 320);
        if (isc & (d > COLL) & (d < CONT)) { att_sum += (double)(d * d); att_cnt++; }
    }

    __shared__ double sd[256], sp[256], sa[256];
    __shared__ int    cp[256], ca[256];
    sd[tid] = sum_d; sp[tid] = pen_sum; sa[tid] = att_sum;
    cp[tid] = pen_cnt; ca[tid] = att_cnt;
    __syncthreads();
    for (int off = 128; off > 0; off >>= 1) {
        if (tid < off) {
            sd[tid] += sd[tid + off]; sp[tid] += sp[tid + off];
            sa[tid] += sa[tid + off];
            cp[tid] += cp[tid + off]; ca[tid] += ca[tid + off];
        }
        __syncthreads();
    }
    if (tid == 0) {
        const double pen_loss = cp[0] > 0 ? sp[0] / (double)cp[0] : 0.0;
        const double att_loss = ca[0] > 0 ? sa[0] / (double)ca[0] : 0.0;
        out[0] = (float)(100.0 * pen_loss + 10.0 * att_loss);
        out[1] = (float)pen_loss;
        out[2] = (float)att_loss;
        out[3] = (float)(sd[0] / (double)total);
        out[4] = (float)ca[0];
        out[5] = (float)cp[0];
    }
}

extern "C" void kernel_launch(void* const* d_in, const int* in_sizes, int n_in,
                              void* d_out, int out_size, void* d_ws, size_t ws_size,
                              hipStream_t stream) {
    const float* hand = (const float*)d_in[0];  // [B, 778, 3] fp32
    const float* obj  = (const float*)d_in[1];  // [B, V, 3]   fp32
    // d_in[2]/d_in[3] (faces): unused by the loss

    const int B = in_sizes[0] / (NH * 3);
    const int V = in_sizes[1] / (B * 3);
    const int nchunks = (V + CHUNKP - 1) / CHUNKP;

    unsigned int* minb = (unsigned int*)d_ws;   // [B*NH] min-d2 bit patterns

    // init mins to 0x7F7F7F7F (~3.39e38f; > any real d2)
    hipMemsetAsync(d_ws, 0x7F, (size_t)B * NH * sizeof(unsigned int), stream);

    dim3 grid(NBX, nchunks, B);
    nn_min_kernel<<<grid, BLK, 0, stream>>>(hand, obj, minb, V);
    finalize_kernel<<<1, 256, 0, stream>>>(minb, (float*)d_out, B);
}

// Round 10
// 107.603 us; speedup vs baseline: 1.1294x; 1.0445x over previous
//
#include <hip/hip_runtime.h>
#include <math.h>

typedef float v2f __attribute__((ext_vector_type(2)));

// Problem constants
constexpr int NH     = 778;   // hand verts per batch
constexpr int T      = 16;    // hand points per tile (SGPR-resident)
constexpr int G      = 4;     // tiles per block -> 64 hand points
constexpr int NBX    = (NH + G * T - 1) / (G * T);   // 13
constexpr int BLK    = 256;   // 4 waves
constexpr int CHUNKP = 2560;  // obj points per block chunk
constexpr int LPP    = CHUNKP / BLK;   // 10 obj points per lane
constexpr int PPAIR  = LPP / 2;        // 5 packed point-pairs per lane

// ---------------------------------------------------------------------------
// NN kernel, R10.
// R9 post-mortem: VGPR_Count=36 proved the compiler's occupancy heuristic
// sank the 40-reg obj stash back into the g-loop (reload+rescale+select every
// pass). Fixes: (1) __launch_bounds__(256,2) -> 256-VGPR budget, stash stays
// resident; (2) clamped obj index instead of q-sentinel (duplicate valid
// points never change a min -> zero select logic); (3) packed fp32: obj
// point-pairs in v2f, __builtin_elementwise_fma -> v_pk_fma_f32 (gfx90a+
// VOP3P), min via v_min3 of the two halves: 2 VALU instr per hand x obj pair.
//   d2' = |o|^2 - 2 h.o     (|h|^2 folded in the epilogue)
// Epilogue per tile: per-wave LDS transpose (stride-65 rows, conflict-free)
// + 2 shfl; pre-checked atomicMin on uint bits (valid order, non-neg floats).
// g-loop NOT unrolled: resident body stays I$-small (R7 lesson).
// ---------------------------------------------------------------------------
__global__ __launch_bounds__(BLK, 2) void nn_min_kernel(
    const float* __restrict__ hand,  // [B, NH, 3]
    const float* __restrict__ obj,   // [B, V, 3]
    unsigned int* __restrict__ minb, // [B*NH]
    int V)
{
    __shared__ float s_red[4][16 * 65];   // 16.6 KB per-wave transpose
    const int bx   = blockIdx.x;   // hand tile group
    const int c    = blockIdx.y;   // obj chunk
    const int b    = blockIdx.z;   // batch
    const int tid  = threadIdx.x;
    const int wave = tid >> 6;
    const int lane = tid & 63;
    const int r    = lane & 15;
    const int seg  = lane >> 4;

    // per-lane obj stash: 5 point-pairs as v2f (-2x,-2y,-2z,q), index clamped
    // (duplicates of point V-1 are valid points -> min unaffected, no sentinel)
    const float* ob = obj + (size_t)b * V * 3;
    const int base = c * CHUNKP + tid;
    v2f ox2[PPAIR], oy2[PPAIR], oz2[PPAIR], oq2[PPAIR];
#pragma unroll
    for (int p = 0; p < PPAIR; ++p) {
        const int ja = min(base + (2 * p + 0) * BLK, V - 1);
        const int jb = min(base + (2 * p + 1) * BLK, V - 1);
        const float xa = ob[3 * ja + 0], ya = ob[3 * ja + 1], za = ob[3 * ja + 2];
        const float xb = ob[3 * jb + 0], yb = ob[3 * jb + 1], zb = ob[3 * jb + 2];
        ox2[p] = (v2f){-2.f * xa, -2.f * xb};
        oy2[p] = (v2f){-2.f * ya, -2.f * yb};
        oz2[p] = (v2f){-2.f * za, -2.f * zb};
        oq2[p] = (v2f){fmaf(xa, xa, fmaf(ya, ya, za * za)),
                       fmaf(xb, xb, fmaf(yb, yb, zb * zb))};
    }

    const float* hb = hand + (size_t)b * NH * 3;  // uniform base
    float* sw = &s_red[wave][0];

#pragma unroll 1   // keep resident body small: I$-safe
    for (int g = 0; g < G; ++g) {
        // hand tile: uniform addresses -> s_load into SGPRs
        float hx[T], hy[T], hz[T];
#pragma unroll
        for (int t = 0; t < T; ++t) {
            const int h = min((bx * G + g) * T + t, NH - 1);
            hx[t] = hb[3 * h + 0];
            hy[t] = hb[3 * h + 1];
            hz[t] = hb[3 * h + 2];
        }

        float m[T];
#pragma unroll
        for (int t = 0; t < T; ++t) m[t] = 3.4e38f;

#pragma unroll
        for (int p = 0; p < PPAIR; ++p) {
#pragma unroll
            for (int t = 0; t < T; ++t) {
                // v_pk_fma_f32 x3 + v_min3_f32: 2 instr per hand-obj pair
                v2f a = __builtin_elementwise_fma(ox2[p], (v2f){hx[t], hx[t]}, oq2[p]);
                a = __builtin_elementwise_fma(oy2[p], (v2f){hy[t], hy[t]}, a);
                a = __builtin_elementwise_fma(oz2[p], (v2f){hz[t], hz[t]}, a);
                m[t] = fminf(fminf(a.x, a.y), m[t]);   // v_min3
            }
        }

        // fold |h|^2, transpose within the wave (row stride 65: conflict-free)
#pragma unroll
        for (int t = 0; t < T; ++t) {
            const float hq = fmaf(hx[t], hx[t], fmaf(hy[t], hy[t], hz[t] * hz[t]));
            sw[t * 65 + lane] = m[t] + hq;
        }
        __builtin_amdgcn_wave_barrier();

        float v = 3.4e38f;
        const int rbase = r * 65 + seg * 16;
#pragma unroll
        for (int j = 0; j < 16; ++j) v = fminf(v, sw[rbase + j]);
        __builtin_amdgcn_wave_barrier();   // before next tile overwrites

        v = fminf(v, __shfl_xor(v, 16));
        v = fminf(v, __shfl_xor(v, 32));

        if (seg == 0) {
            const int hidx = (bx * G + g) * T + r;
            if (hidx < NH) {
                const unsigned bits = __float_as_uint(fmaxf(v, 0.f));
                unsigned int* p = &minb[b * NH + hidx];
                // stale read >= true min => skipping when bits >= *p is safe
                if (bits < *((volatile unsigned int*)p)) atomicMin(p, bits);
            }
        }
    }
}

// Final reduction -> 6 scalar outputs
__global__ __launch_bounds__(256) void finalize_kernel(
    const unsigned int* __restrict__ minb, float* __restrict__ out, int B)
{
    constexpr float COLL = 0.005f;
    constexpr float CONT = 0.01f;
    const int total = B * NH;
    const int tid = threadIdx.x;

    double sum_d = 0.0, pen_sum = 0.0, att_sum = 0.0;
    int pen_cnt = 0, att_cnt = 0;
    for (int i = tid; i < total; i += 256) {
        const float d = sqrtf(__uint_as_float(minb[i]));
        sum_d += (double)d;
        if (d < COLL) { const float t = COLL - d; pen_sum += (double)(t * t); pen_cnt++; }
        const int n = i % NH;
        const bool isc = (n == 745) | (n == 317) | (n == 444) | (n == 556) |
                         (n == 673) | (n == 95)  | (n == 182) | (n == 234) |
                         (n == 279) | (n == 320);
        if (isc & (d > COLL) & (d < CONT)) { att_sum += (double)(d * d); att_cnt++; }
    }

    __shared__ double sd[256], sp[256], sa[256];
    __shared__ int    cp[256], ca[256];
    sd[tid] = sum_d; sp[tid] = pen_sum; sa[tid] = att_sum;
    cp[tid] = pen_cnt; ca[tid] = att_cnt;
    __syncthreads();
    for (int off = 128; off > 0; off >>= 1) {
        if (tid < off) {
            sd[tid] += sd[tid + off]; sp[tid] += sp[tid + off];
            sa[tid] += sa[tid + off];
            cp[tid] += cp[tid + off]; ca[tid] += ca[tid + off];
        }
        __syncthreads();
    }
    if (tid == 0) {
        const double pen_loss = cp[0] > 0 ? sp[0] / (double)cp[0] : 0.0;
        const double att_loss = ca[0] > 0 ? sa[0] / (double)ca[0] : 0.0;
        out[0] = (float)(100.0 * pen_loss + 10.0 * att_loss);
        out[1] = (float)pen_loss;
        out[2] = (float)att_loss;
        out[3] = (float)(sd[0] / (double)total);
        out[4] = (float)ca[0];
        out[5] = (float)cp[0];
    }
}

extern "C" void kernel_launch(void* const* d_in, const int* in_sizes, int n_in,
                              void* d_out, int out_size, void* d_ws, size_t ws_size,
                              hipStream_t stream) {
    const float* hand = (const float*)d_in[0];  // [B, 778, 3] fp32
    const float* obj  = (const float*)d_in[1];  // [B, V, 3]   fp32
    // d_in[2]/d_in[3] (faces): unused by the loss

    const int B = in_sizes[0] / (NH * 3);
    const int V = in_sizes[1] / (B * 3);
    const int nchunks = (V + CHUNKP - 1) / CHUNKP;

    unsigned int* minb = (unsigned int*)d_ws;   // [B*NH] min-d2 bit patterns

    // init mins to 0x7F7F7F7F (~3.39e38f; > any real d2)
    hipMemsetAsync(d_ws, 0x7F, (size_t)B * NH * sizeof(unsigned int), stream);

    dim3 grid(NBX, nchunks, B);
    nn_min_kernel<<<grid, BLK, 0, stream>>>(hand, obj, minb, V);
    finalize_kernel<<<1, 256, 0, stream>>>(minb, (float*)d_out, B);
}